// Round 1
// baseline (230.192 us; speedup 1.0000x reference)
//
#include <hip/hip_runtime.h>

// Cascaded convex upsampling (SEAFLOW3DP), fused in PAIRS of x2 stages:
//   K1: x16 -> x8 -> x4   (mask16 at coarse, mask8 at mid)  -> ws
//   K2: x4  -> x2 -> x1   (mask4  at coarse, mask2 at mid)  -> d_out
//
// Per block: 8x8 coarse tile.
//   Phase 1: compute the mid-level (2Hc,2Wc) field on an 18x18 tile WITH
//            1-pixel halo, store in LDS (stride 19 -> max 2-way bank alias,
//            free). Out-of-image halo = 0 == the mid-level zero padding the
//            second unfold needs.
//   Phase 2: one thread per mid-parent (16x16 = 256): 36 maskB loads + 36
//            exps + 27 LDS taps + 144 FMA -> 2x2 fine outputs x 3 channels.
//
// Softmax semantics: zero-padded taps contribute 0 to the numerator but keep
// their weight in the denominator -> zero the TAP, not the weight.
// Flow premul=2 applied per stage (so x4 total through a pair), dz premul=1.

#define NB 4

template <int Hc, int Wc>
__global__ __launch_bounds__(256) void fused_up4(
    const float* __restrict__ flowIn,  // (NB,2,Hc,Wc)
    const float* __restrict__ dzIn,    // (NB,1,Hc,Wc)
    const float* __restrict__ maskA,   // (NB,36,Hc,Wc)      coarse-level mask
    const float* __restrict__ maskB,   // (NB,36,2Hc,2Wc)    mid-level mask
    float* __restrict__ flowOut,       // ch0 at n*flowOutBS, ch1 at +4Hc*4Wc
    float* __restrict__ dzOut,         // at n*dzOutBS
    int flowOutBS, int dzOutBS)
{
    constexpr int HWc = Hc * Wc;
    constexpr int Hm = 2 * Hc, Wm = 2 * Wc;
    constexpr int HWm = Hm * Wm;
    constexpr int W4 = 4 * Wc;
    constexpr int TBX = Wc / 8, TBY = Hc / 8;

    __shared__ float smx[18][19], smy[18][19], smz[18][19];

    int b = blockIdx.x;
    int tX = b % TBX;
    int t2 = b / TBX;
    int tY = t2 % TBY;
    int n  = t2 / TBY;

    int h0  = tY * 8, w0 = tX * 8;       // coarse tile origin
    int m0y = 2 * h0, m0x = 2 * w0;      // mid tile origin

    const float* fb = flowIn + (size_t)n * 2 * HWc;
    const float* db = dzIn   + (size_t)n * HWc;
    const float* mA = maskA  + (size_t)n * 36 * HWc;
    const float* mB = maskB  + (size_t)n * 36 * HWm;

    int tid = threadIdx.x;

    // ---------------- phase 1: mid tile (18x18 incl. halo) ----------------
    for (int i = tid; i < 324; i += 256) {
        int ym = i / 18, xm = i % 18;
        int my = m0y - 1 + ym, mx = m0x - 1 + xm;
        float vx = 0.f, vy = 0.f, vz = 0.f;
        if ((unsigned)my < (unsigned)Hm && (unsigned)mx < (unsigned)Wm) {
            int pcy = my >> 1, pcx = mx >> 1;           // coarse parent
            int q = (my & 1) * 2 + (mx & 1);            // quadrant
            const float* ma = mA + (size_t)pcy * Wc + pcx;
            float e[9];
#pragma unroll
            for (int k = 0; k < 9; ++k) e[k] = __expf(ma[(size_t)(k * 4 + q) * HWc]);
            float s = 0.f, ax = 0.f, ay = 0.f, az = 0.f;
#pragma unroll
            for (int kh = 0; kh < 3; ++kh) {
                int hh = pcy + kh - 1;
                bool vh = (unsigned)hh < (unsigned)Hc;
                int hcl = min(max(hh, 0), Hc - 1);
#pragma unroll
                for (int kw = 0; kw < 3; ++kw) {
                    int ww = pcx + kw - 1;
                    bool v = vh && ((unsigned)ww < (unsigned)Wc);
                    int wcl = min(max(ww, 0), Wc - 1);
                    int o = hcl * Wc + wcl;
                    int k = kh * 3 + kw;
                    float x = fb[o], y = fb[HWc + o], z = db[o];
                    x = v ? x : 0.f; y = v ? y : 0.f; z = v ? z : 0.f;
                    float w = e[k];
                    s  += w;
                    ax += w * x;
                    ay += w * y;
                    az += w * z;
                }
            }
            float inv = __builtin_amdgcn_rcpf(s);
            float fs = 2.0f * inv;   // per-stage flow premul
            vx = ax * fs; vy = ay * fs; vz = az * inv;
        }
        smx[ym][xm] = vx; smy[ym][xm] = vy; smz[ym][xm] = vz;
    }
    __syncthreads();

    // ------------- phase 2: one mid-parent per thread (16x16) -------------
    int px = tid & 15, py = tid >> 4;
    int pmy = m0y + py, pmx = m0x + px;                 // mid coords (in range)

    const float* mbp = mB + (size_t)pmy * Wm + pmx;
    float e[36];
#pragma unroll
    for (int c = 0; c < 36; ++c) e[c] = __expf(mbp[(size_t)c * HWm]);

    float tx[9], ty[9], tz[9];
#pragma unroll
    for (int kh = 0; kh < 3; ++kh)
#pragma unroll
        for (int kw = 0; kw < 3; ++kw) {
            int k = kh * 3 + kw;
            tx[k] = smx[py + kh][px + kw];
            ty[k] = smy[py + kh][px + kw];
            tz[k] = smz[py + kh][px + kw];
        }

    float* fo0 = flowOut + (size_t)n * flowOutBS;
    float* fo1 = fo0 + (size_t)(4 * Hc) * W4;           // channel stride
    float* dzo = dzOut + (size_t)n * dzOutBS;

#pragma unroll
    for (int sy = 0; sy < 2; ++sy) {
        float2 rx, ry, rz;
#pragma unroll
        for (int sx = 0; sx < 2; ++sx) {
            int q = sy * 2 + sx;
            float s = 0.f, ax = 0.f, ay = 0.f, az = 0.f;
#pragma unroll
            for (int k = 0; k < 9; ++k) {
                float w = e[k * 4 + q];
                s  += w;
                ax += w * tx[k];
                ay += w * ty[k];
                az += w * tz[k];
            }
            float inv = __builtin_amdgcn_rcpf(s);
            float fs = 2.0f * inv;
            if (sx == 0) { rx.x = ax * fs; ry.x = ay * fs; rz.x = az * inv; }
            else         { rx.y = ax * fs; ry.y = ay * fs; rz.y = az * inv; }
        }
        size_t oo = (size_t)(2 * pmy + sy) * W4 + 2 * pmx;
        *(float2*)(fo0 + oo) = rx;
        *(float2*)(fo1 + oo) = ry;
        *(float2*)(dzo + oo) = rz;
    }
}

extern "C" void kernel_launch(void* const* d_in, const int* in_sizes, int n_in,
                              void* d_out, int out_size, void* d_ws, size_t ws_size,
                              hipStream_t stream) {
    const float* flow16 = (const float*)d_in[0];  // (4,2,48,64)
    const float* dz16   = (const float*)d_in[1];  // (4,1,48,64)
    const float* mask16 = (const float*)d_in[2];  // (4,36,48,64)
    const float* mask8  = (const float*)d_in[3];  // (4,36,96,128)
    const float* mask4  = (const float*)d_in[4];  // (4,36,192,256)
    const float* mask2  = (const float*)d_in[5];  // (4,36,384,512)

    float* ws = (float*)d_ws;
    float* flowB = ws;                            // (4,2,192,256)
    float* dzB   = flowB + 4 * 2 * 192 * 256;     // (4,1,192,256)

    float* out = (float*)d_out;                   // (4,3,768,1024)
    const int HW1 = 768 * 1024;
    const int HW4 = 192 * 256;

    // K1: x16 -> x4 (stages 1+2 fused). 4*6*8 = 192 blocks.
    hipLaunchKernelGGL((fused_up4<48, 64>), dim3(NB * 6 * 8), dim3(256), 0, stream,
                       flow16, dz16, mask16, mask8, flowB, dzB, 2 * HW4, HW4);
    // K2: x4 -> x1 (stages 3+4 fused), straight into d_out. 4*24*32 = 3072 blocks.
    hipLaunchKernelGGL((fused_up4<192, 256>), dim3(NB * 24 * 32), dim3(256), 0, stream,
                       flowB, dzB, mask4, mask2, out, out + 2 * HW1, 3 * HW1, 3 * HW1);
}

// Round 2
// 222.699 us; speedup vs baseline: 1.0336x; 1.0336x over previous
//
#include <hip/hip_runtime.h>

// Cascaded convex upsampling (SEAFLOW3DP), fused in PAIRS of x2 stages:
//   K1: x16 -> x8 -> x4   (mask16 at coarse, mask8 at mid)  -> ws
//   K2: x4  -> x2 -> x1   (mask4  at coarse, mask2 at mid)  -> d_out
//
// Tile = TH x TW MID-level pixels per block (one thread per mid "parent"),
// block = TH*TW threads. TW=32 so each wave row reads 32 consecutive
// floats (= one aligned 128B line) of the big mid-level mask.
//
// Phase 0: prefetch this thread's 36 raw maskB values into registers --
//          their (HBM) latency hides under phase 1.
// Phase 1: compute the mid-level field on (TH+2)x(TW+2) incl. 1-px halo,
//          store to LDS (row stride TW+3 == 3 mod 32 -> 2-way alias, free).
//          Out-of-image halo = 0 == the zero padding the 2nd unfold needs.
// Phase 2: exp the prefetched mask, 27 LDS taps, 144 FMA -> 2x2 fine
//          outputs x 3 channels, 256B-contiguous stores.
//
// Softmax semantics: zero-padded taps contribute 0 to the numerator but
// keep their weight in the denominator -> zero the TAP, not the weight.
// Flow premul=2 applied per stage, dz premul=1.

#define NB 4

template <int Hc, int Wc, int TH, int TW, int NT>
__global__ __launch_bounds__(NT) void fused_up4(
    const float* __restrict__ flowIn,  // (NB,2,Hc,Wc)
    const float* __restrict__ dzIn,    // (NB,1,Hc,Wc)
    const float* __restrict__ maskA,   // (NB,36,Hc,Wc)      coarse-level mask
    const float* __restrict__ maskB,   // (NB,36,2Hc,2Wc)    mid-level mask
    float* __restrict__ flowOut,       // ch0 at n*flowOutBS, ch1 at +4Hc*4Wc
    float* __restrict__ dzOut,         // at n*dzOutBS
    int flowOutBS, int dzOutBS)
{
    constexpr int HWc = Hc * Wc;
    constexpr int Hm = 2 * Hc, Wm = 2 * Wc;
    constexpr int HWm = Hm * Wm;
    constexpr int W4 = 4 * Wc;
    constexpr int TBX = Wm / TW, TBY = Hm / TH;
    constexpr int RH = TH + 2, RW = TW + 2;
    constexpr int NR = RH * RW;

    __shared__ float smx[RH][RW + 1], smy[RH][RW + 1], smz[RH][RW + 1];

    int b = blockIdx.x;
    int tX = b % TBX;
    int t2 = b / TBX;
    int tY = t2 % TBY;
    int n  = t2 / TBY;

    int m0y = tY * TH, m0x = tX * TW;    // mid tile origin

    int tid = threadIdx.x;
    int px = tid % TW, py = tid / TW;
    int pmy = m0y + py, pmx = m0x + px;  // this thread's mid parent (in range)

    // ---- phase 0: prefetch phase-2 mask (raw) -- hides under phase 1 ----
    const float* mbp = maskB + (size_t)n * 36 * HWm + (size_t)pmy * Wm + pmx;
    float e[36];
#pragma unroll
    for (int c = 0; c < 36; ++c) e[c] = mbp[(size_t)c * HWm];

    // ---------------- phase 1: mid tile (TH+2 x TW+2 incl. halo) ----------
    const float* fb = flowIn + (size_t)n * 2 * HWc;
    const float* db = dzIn   + (size_t)n * HWc;
    const float* mA = maskA  + (size_t)n * 36 * HWc;

#pragma unroll
    for (int it = 0; it < (NR + NT - 1) / NT; ++it) {
        int i = it * NT + tid;
        if (i < NR) {
            int ym = i / RW, xm = i % RW;
            int my = m0y - 1 + ym, mx = m0x - 1 + xm;
            float vx = 0.f, vy = 0.f, vz = 0.f;
            if ((unsigned)my < (unsigned)Hm && (unsigned)mx < (unsigned)Wm) {
                int pcy = my >> 1, pcx = mx >> 1;        // coarse parent
                int q = (my & 1) * 2 + (mx & 1);         // quadrant
                const float* ma = mA + (size_t)pcy * Wc + pcx;
                float e9[9];
#pragma unroll
                for (int k = 0; k < 9; ++k)
                    e9[k] = __expf(ma[(size_t)(k * 4 + q) * HWc]);
                float s = 0.f, ax = 0.f, ay = 0.f, az = 0.f;
#pragma unroll
                for (int kh = 0; kh < 3; ++kh) {
                    int hh = pcy + kh - 1;
                    bool vh = (unsigned)hh < (unsigned)Hc;
                    int hcl = min(max(hh, 0), Hc - 1);
#pragma unroll
                    for (int kw = 0; kw < 3; ++kw) {
                        int ww = pcx + kw - 1;
                        bool v = vh && ((unsigned)ww < (unsigned)Wc);
                        int wcl = min(max(ww, 0), Wc - 1);
                        int o = hcl * Wc + wcl;
                        int k = kh * 3 + kw;
                        float x = fb[o], y = fb[HWc + o], z = db[o];
                        x = v ? x : 0.f; y = v ? y : 0.f; z = v ? z : 0.f;
                        float w = e9[k];
                        s  += w;
                        ax += w * x;
                        ay += w * y;
                        az += w * z;
                    }
                }
                float inv = __builtin_amdgcn_rcpf(s);
                float fs = 2.0f * inv;   // per-stage flow premul
                vx = ax * fs; vy = ay * fs; vz = az * inv;
            }
            smx[ym][xm] = vx; smy[ym][xm] = vy; smz[ym][xm] = vz;
        }
    }

    // exp the prefetched mask (independent of LDS; fills barrier wait)
#pragma unroll
    for (int c = 0; c < 36; ++c) e[c] = __expf(e[c]);

    __syncthreads();

    // ------------- phase 2: one mid-parent per thread -------------
    float tx[9], ty[9], tz[9];
#pragma unroll
    for (int kh = 0; kh < 3; ++kh)
#pragma unroll
        for (int kw = 0; kw < 3; ++kw) {
            int k = kh * 3 + kw;
            tx[k] = smx[py + kh][px + kw];
            ty[k] = smy[py + kh][px + kw];
            tz[k] = smz[py + kh][px + kw];
        }

    float* fo0 = flowOut + (size_t)n * flowOutBS;
    float* fo1 = fo0 + (size_t)(4 * Hc) * W4;           // channel stride
    float* dzo = dzOut + (size_t)n * dzOutBS;

#pragma unroll
    for (int sy = 0; sy < 2; ++sy) {
        float2 rx, ry, rz;
#pragma unroll
        for (int sx = 0; sx < 2; ++sx) {
            int q = sy * 2 + sx;
            float s = 0.f, ax = 0.f, ay = 0.f, az = 0.f;
#pragma unroll
            for (int k = 0; k < 9; ++k) {
                float w = e[k * 4 + q];
                s  += w;
                ax += w * tx[k];
                ay += w * ty[k];
                az += w * tz[k];
            }
            float inv = __builtin_amdgcn_rcpf(s);
            float fs = 2.0f * inv;
            if (sx == 0) { rx.x = ax * fs; ry.x = ay * fs; rz.x = az * inv; }
            else         { rx.y = ax * fs; ry.y = ay * fs; rz.y = az * inv; }
        }
        size_t oo = (size_t)(2 * pmy + sy) * W4 + 2 * pmx;
        *(float2*)(fo0 + oo) = rx;
        *(float2*)(fo1 + oo) = ry;
        *(float2*)(dzo + oo) = rz;
    }
}

extern "C" void kernel_launch(void* const* d_in, const int* in_sizes, int n_in,
                              void* d_out, int out_size, void* d_ws, size_t ws_size,
                              hipStream_t stream) {
    const float* flow16 = (const float*)d_in[0];  // (4,2,48,64)
    const float* dz16   = (const float*)d_in[1];  // (4,1,48,64)
    const float* mask16 = (const float*)d_in[2];  // (4,36,48,64)
    const float* mask8  = (const float*)d_in[3];  // (4,36,96,128)
    const float* mask4  = (const float*)d_in[4];  // (4,36,192,256)
    const float* mask2  = (const float*)d_in[5];  // (4,36,384,512)

    float* ws = (float*)d_ws;
    float* flowB = ws;                            // (4,2,192,256)
    float* dzB   = flowB + 4 * 2 * 192 * 256;     // (4,1,192,256)

    float* out = (float*)d_out;                   // (4,3,768,1024)
    const int HW1 = 768 * 1024;
    const int HW4 = 192 * 256;

    // K1: x16 -> x4. mid = 96x128, tile 4x32 -> 4*24*4 = 384 blocks of 128.
    hipLaunchKernelGGL((fused_up4<48, 64, 4, 32, 128>),
                       dim3(NB * (96 / 4) * (128 / 32)), dim3(128), 0, stream,
                       flow16, dz16, mask16, mask8, flowB, dzB, 2 * HW4, HW4);
    // K2: x4 -> x1. mid = 384x512, tile 8x32 -> 4*48*16 = 3072 blocks of 256.
    hipLaunchKernelGGL((fused_up4<192, 256, 8, 32, 256>),
                       dim3(NB * (384 / 8) * (512 / 32)), dim3(256), 0, stream,
                       flowB, dzB, mask4, mask2, out, out + 2 * HW1, 3 * HW1, 3 * HW1);
}